// Round 5
// baseline (186.076 us; speedup 1.0000x reference)
//
#include <hip/hip_runtime.h>

#define V_VOCAB 50000
#define K_DIM   300
#define NROWS   1024
#define LEN     64
#define NBC     392     // col-blocks per side: 392*128 = 50176 >= 50000
#define CGS     784     // col-groups (waves of 64 cols) per side = NBC*2
#define KS      19      // k-steps of 16: covers k=0..303 (300 dims + bias@300)
#define PASSES  32      // 32 passes x 32 rows = 1024 rows
#define LOG2E   1.44269504088896f

typedef __attribute__((ext_vector_type(8)))  short bf16x8;
typedef __attribute__((ext_vector_type(16))) float f32x16;

static __device__ __forceinline__ unsigned short f2bf(float f) {
    unsigned int u = __builtin_bit_cast(unsigned int, f);
    u = u + 0x7fffu + ((u >> 16) & 1u);   // RNE
    return (unsigned short)(u >> 16);
}

static __device__ __forceinline__ f32x16 zero16() {
    f32x16 z;
#pragma unroll
    for (int i = 0; i < 16; ++i) z[i] = 0.0f;
    return z;
}

static __device__ __forceinline__ void gload_lds16(const void* g, void* l) {
    __builtin_amdgcn_global_load_lds((const __attribute__((address_space(1))) void*)g,
                                     (__attribute__((address_space(3))) void*)l, 16, 0, 0);
}

// ---------------------------------------------------------------------------
// Kernel 1: samp_hid f32 [1024][300] -> bf16 B-fragment buffer for 32x32x16,
// pre-scaled by log2(e) so the GEMM epilogue can use exp2 directly.
// Frag (rblk, ks): lane l holds Zs[rblk*32 + (l&31)][ks*16 + (l>>5)*8 + j].
// k==300 -> log2e (bias slot), k>300 -> 0.
__global__ void zbf_kernel(const float* __restrict__ z, unsigned short* __restrict__ zbf) {
    int t = blockIdx.x * 256 + threadIdx.x;      // 0..38911 = 32 rblk * 19 ks * 64 lanes
    int l    = t & 63;
    int rest = t >> 6;
    int ks   = rest % KS;
    int rblk = rest / KS;
    int row  = rblk * 32 + (l & 31);
    int k0   = ks * 16 + (l >> 5) * 8;
    unsigned short o[8];
#pragma unroll
    for (int j = 0; j < 8; ++j) {
        int k = k0 + j;
        float v = (k < K_DIM) ? z[row * K_DIM + k] * LOG2E
                              : ((k == K_DIM) ? LOG2E : 0.0f);
        o[j] = f2bf(v);
    }
    ushort4* p = (ushort4*)(zbf + (size_t)t * 8);
    p[0] = make_ushort4(o[0], o[1], o[2], o[3]);
    p[1] = make_ushort4(o[4], o[5], o[6], o[7]);
}

// ---------------------------------------------------------------------------
// Kernel 2: D[c][m] = log2e*(E[c].Z[m] + bias_c); partial[cg][m] = sum_c 2^D.
// 64 cols/wave (a0,a1 = 152 VGPR) -> 19 ds_read : 38 MFMA per pass (1:2).
// 2-wave blocks, 38,912 B LDS -> 4 blocks/CU. waves_per_eu(2,2) pins the
// 256-VGPR budget so the a-fragments cannot spill.
__attribute__((amdgpu_waves_per_eu(2, 2)))
__global__ void __launch_bounds__(128)
gemm_kernel(const unsigned short* __restrict__ zbf,
            const float* __restrict__ emb_x,
            const float* __restrict__ emb_y,
            const float* __restrict__ bias_x,
            const float* __restrict__ bias_y,
            float* __restrict__ partial,
            float* __restrict__ lsesum,
            int accmode) {
    __shared__ unsigned short Zs[2][9728];   // 2 x 19,456 B = 38,912 B

    const int tid  = threadIdx.x;
    const int lane = tid & 63;
    const int w    = tid >> 6;               // 0..1
    const int side = blockIdx.y;
    const int bc   = blockIdx.x;
    const float* eg = side ? emb_y : emb_x;
    const float* bg = side ? bias_y : bias_x;

    // ---- start staging pass 0 while we load E fragments (10 issues/wave)
    {
        const unsigned short* src = zbf;
#pragma unroll
        for (int i = 0; i < 10; ++i) {
            int q = w * 10 + i;
            if (q > 18) q = 18;              // idempotent dup (wave 1)
            gload_lds16(src + (size_t)q * 512 + lane * 8, &Zs[0][q * 512]);
        }
    }

    // ---- load E a-fragments into registers (once per block): 64 cols/wave
    bf16x8 a0[KS], a1[KS];
#pragma unroll
    for (int cb = 0; cb < 2; ++cb) {
        const int c  = bc * 128 + w * 64 + cb * 32 + (lane & 31);
        const bool cv = (c < V_VOCAB);
        const float* erow = eg + (size_t)c * K_DIM;
        const int khi = (lane >> 5) * 8;
#pragma unroll
        for (int ks = 0; ks < KS; ++ks) {
            const int k0 = ks * 16 + khi;
            float f[8];
            if (k0 + 8 <= K_DIM) {
                float4 u  = cv ? *(const float4*)(erow + k0)     : make_float4(0, 0, 0, 0);
                float4 v2 = cv ? *(const float4*)(erow + k0 + 4) : make_float4(0, 0, 0, 0);
                f[0] = u.x;  f[1] = u.y;  f[2] = u.z;  f[3] = u.w;
                f[4] = v2.x; f[5] = v2.y; f[6] = v2.z; f[7] = v2.w;
            } else {
#pragma unroll
                for (int j = 0; j < 8; ++j) {
                    int k = k0 + j;
                    f[j] = (k < K_DIM) ? (cv ? erow[k] : 0.0f)
                         : (k == K_DIM ? (cv ? bg[c] : -3e38f) : 0.0f);
                }
            }
            bf16x8 t;
#pragma unroll
            for (int j = 0; j < 8; ++j) t[j] = (short)f2bf(f[j]);
            if (cb == 0) a0[ks] = t; else a1[ks] = t;
        }
    }

    float* pout = partial + ((size_t)side * CGS + (size_t)bc * 2 + w) * NROWS;
    float* lout = lsesum + side * NROWS;

    int buf = 0;
    for (int p = 0; p < PASSES; ++p) {
        if (p < PASSES - 1) {
            const unsigned short* src = zbf + (size_t)(p + 1) * 9728;
#pragma unroll
            for (int i = 0; i < 10; ++i) {
                int q = w * 10 + i;
                if (q > 18) q = 18;
                gload_lds16(src + (size_t)q * 512 + lane * 8, &Zs[buf ^ 1][q * 512]);
            }
            asm volatile("s_waitcnt vmcnt(10)" ::: "memory");  // this pass's loads done
        } else {
            asm volatile("s_waitcnt vmcnt(0)" ::: "memory");
        }
        __builtin_amdgcn_s_barrier();          // both waves' slices landed
        __builtin_amdgcn_sched_barrier(0);

        const unsigned short* zb = &Zs[buf][0];
        f32x16 acc0 = zero16(), acc1 = zero16();
#pragma unroll
        for (int ks = 0; ks < KS; ++ks) {
            bf16x8 b = *(const bf16x8*)(zb + ((size_t)ks * 64 + lane) * 8);
            acc0 = __builtin_amdgcn_mfma_f32_32x32x16_bf16(a0[ks], b, acc0, 0, 0, 0);
            acc1 = __builtin_amdgcn_mfma_f32_32x32x16_bf16(a1[ks], b, acc1, 0, 0, 0);
        }

        // epilogue: 2^D, sum the wave's 64 vocab cols for each of 32 rows
        float s0 = 0.0f, s1 = 0.0f;
#pragma unroll
        for (int r = 0; r < 16; ++r) {
            s0 += exp2f(acc0[r]);
            s1 += exp2f(acc1[r]);
        }
        float t = s0 + s1;
        t += __shfl_xor(t, 32, 64);
        if (accmode) { if (lane < 32) atomicAdd(lout + p * 32 + lane, t); }
        else         { if (lane < 32) pout[p * 32 + lane] = t; }

        __builtin_amdgcn_s_barrier();          // both waves done reading buf
        buf ^= 1;
    }
}

// ---------------------------------------------------------------------------
// Kernel 3a (partial mode): LSE[side][m] = log( sum_cg partial[cg][m] )
__global__ void lse_kernel(const float* __restrict__ partial, float* __restrict__ lse) {
    __shared__ float red[1024];
    int side = blockIdx.x >> 4;                 // 0..1
    int mg   = blockIdx.x & 15;                 // 16 groups of 64 rows
    int m    = mg * 64 + (threadIdx.x & 63);
    int sg   = threadIdx.x >> 6;                // 0..15 cg-stripes
    const float* p = partial + (size_t)side * CGS * NROWS;
    float s = 0.0f;
    for (int cg = sg; cg < CGS; cg += 16)
        s += p[(size_t)cg * NROWS + m];
    red[threadIdx.x] = s;
    __syncthreads();
    if (threadIdx.x < 64) {
        float t = 0.0f;
#pragma unroll
        for (int j = 0; j < 16; ++j) t += red[threadIdx.x + 64 * j];
        lse[side * NROWS + mg * 64 + threadIdx.x] = logf(t);
    }
}

// Kernel 3b (atomic mode): in-place log of accumulated sums
__global__ void lse_log_kernel(float* __restrict__ lsesum) {
    int g = blockIdx.x * 1024 + threadIdx.x;
    if (g < 2 * NROWS) lsesum[g] = logf(lsesum[g]);
}

// ---------------------------------------------------------------------------
// Kernel 4: gather-SUM: g_b = sum_{valid pos} e_t ; then
// nllpart[side][b] = cnt*LSE - (z_b . g_b + sum bias_t)
__global__ void gatherdot_kernel(const float* __restrict__ z,
                                 const int* __restrict__ tok_x, const int* __restrict__ tok_y,
                                 const float* __restrict__ emb_x, const float* __restrict__ emb_y,
                                 const float* __restrict__ bias_x, const float* __restrict__ bias_y,
                                 const float* __restrict__ lse, float* __restrict__ nllpart) {
    __shared__ float gs[304];
    const int b = blockIdx.x, side = blockIdx.y, tid = threadIdx.x;
    const int* tokp = (side ? tok_y : tok_x) + b * LEN;
    const float* eg = side ? emb_y : emb_x;
    if (tid < K_DIM) {
        float g0 = 0.0f, g1 = 0.0f, g2 = 0.0f, g3 = 0.0f;
#pragma unroll 4
        for (int pos = 0; pos < LEN; pos += 4) {
            int t0 = tokp[pos], t1 = tokp[pos + 1], t2 = tokp[pos + 2], t3 = tokp[pos + 3];
            if (t0) g0 += eg[(size_t)t0 * K_DIM + tid];
            if (t1) g1 += eg[(size_t)t1 * K_DIM + tid];
            if (t2) g2 += eg[(size_t)t2 * K_DIM + tid];
            if (t3) g3 += eg[(size_t)t3 * K_DIM + tid];
        }
        gs[tid] = (g0 + g1) + (g2 + g3);
    }
    __syncthreads();
    if (tid < 64) {
        const float* bg = side ? bias_y : bias_x;
        float dp = 0.0f;
#pragma unroll
        for (int i = 0; i < 5; ++i) {
            int d = tid + i * 64;
            if (d < K_DIM) dp += z[(size_t)b * K_DIM + d] * gs[d];
        }
        int t = tokp[tid];
        float bs = t ? bg[t] : 0.0f;
        float ct = t ? 1.0f : 0.0f;
#pragma unroll
        for (int off = 32; off > 0; off >>= 1) {
            dp += __shfl_xor(dp, off, 64);
            bs += __shfl_xor(bs, off, 64);
            ct += __shfl_xor(ct, off, 64);
        }
        if (tid == 0) nllpart[side * NROWS + b] = ct * lse[side * NROWS + b] - dp - bs;
    }
}

// ---------------------------------------------------------------------------
// Kernel 5: out = mean over b of (nll_x + nll_y)
__global__ void finalize_kernel(const float* __restrict__ nllpart, float* __restrict__ out) {
    __shared__ float r16[16];
    int i = threadIdx.x;   // 0..1023
    float v = nllpart[i] + nllpart[NROWS + i];
#pragma unroll
    for (int off = 32; off > 0; off >>= 1) v += __shfl_xor(v, off, 64);
    if ((i & 63) == 0) r16[i >> 6] = v;
    __syncthreads();
    if (i < 64) {
        float x = (i < 16) ? r16[i] : 0.0f;
#pragma unroll
        for (int off = 8; off > 0; off >>= 1) x += __shfl_xor(x, off, 64);
        if (i == 0) out[0] = x * (1.0f / 1024.0f);
    }
}

// ---------------------------------------------------------------------------
extern "C" void kernel_launch(void* const* d_in, const int* in_sizes, int n_in,
                              void* d_out, int out_size, void* d_ws, size_t ws_size,
                              hipStream_t stream) {
    const float* z      = (const float*)d_in[0];
    const int*   tok_x  = (const int*)d_in[1];
    const int*   tok_y  = (const int*)d_in[2];
    const float* emb_x  = (const float*)d_in[3];
    const float* emb_y  = (const float*)d_in[4];
    const float* bias_x = (const float*)d_in[5];
    const float* bias_y = (const float*)d_in[6];
    float* out = (float*)d_out;

    char* ws = (char*)d_ws;
    const size_t ZBF_B  = 622592;                       // 38912 frags * 16 B
    const size_t PART_B = (size_t)2 * CGS * NROWS * 4;  // 6,422,528 B
    const size_t need   = ZBF_B + PART_B + 8192 + 8192;

    unsigned short* zbf = (unsigned short*)ws;
    zbf_kernel<<<152, 256, 0, stream>>>(z, zbf);

    if (ws_size >= need) {
        float* partial = (float*)(ws + ZBF_B);
        float* lse     = (float*)(ws + ZBF_B + PART_B);
        float* nllpart = (float*)(ws + ZBF_B + PART_B + 8192);
        gemm_kernel<<<dim3(NBC, 2), 128, 0, stream>>>(zbf, emb_x, emb_y, bias_x, bias_y,
                                                      partial, lse /*unused*/, 0);
        lse_kernel<<<32, 1024, 0, stream>>>(partial, lse);
        gatherdot_kernel<<<dim3(NROWS, 2), 320, 0, stream>>>(z, tok_x, tok_y, emb_x, emb_y,
                                                             bias_x, bias_y, lse, nllpart);
        finalize_kernel<<<1, 1024, 0, stream>>>(nllpart, out);
    } else {
        // compact fallback: accumulate exp-sums with float atomics (error << tol)
        float* lse     = (float*)(ws + ZBF_B);
        float* nllpart = (float*)(ws + ZBF_B + 8192);
        hipMemsetAsync(lse, 0, 8192, stream);
        gemm_kernel<<<dim3(NBC, 2), 128, 0, stream>>>(zbf, emb_x, emb_y, bias_x, bias_y,
                                                      nllpart /*unused*/, lse, 1);
        lse_log_kernel<<<2, 1024, 0, stream>>>(lse);
        gatherdot_kernel<<<dim3(NROWS, 2), 320, 0, stream>>>(z, tok_x, tok_y, emb_x, emb_y,
                                                             bias_x, bias_y, lse, nllpart);
        finalize_kernel<<<1, 1024, 0, stream>>>(nllpart, out);
    }
}